// Round 7
// baseline (549.492 us; speedup 1.0000x reference)
//
#include <hip/hip_runtime.h>
#include <hip/hip_bf16.h>
#include <math.h>

typedef __hip_bfloat16 bf16;
typedef __attribute__((ext_vector_type(8))) short short8;
typedef __attribute__((ext_vector_type(4))) float f32x4;

#define B_ 512
#define T_ 10
#define N_ 50
#define H_ 200
#define E_ 10000
#define R_ 200
#define K3 600   // 3*H

__device__ __forceinline__ float b2f(bf16 x){ return __bfloat162float(x); }
__device__ __forceinline__ float sigm(float x){ return 1.f / (1.f + expf(-x)); }

// ---------------------------------------------------------------- init
__global__ void k_init(float* lossacc){ if(threadIdx.x < 4) lossacc[threadIdx.x] = 0.f; }

// ---------------------------------------------------------------- packs
// Wn2[side][256][256]: rows 0-199 = Wa_side[g][0:200], rest 0
__global__ __launch_bounds__(256) void k_pack_wn2(
    const float* __restrict__ Wa0, const float* __restrict__ Wa1, bf16* __restrict__ Wn2)
{
  int r = blockIdx.x, side = blockIdx.y;
  const float* Wa = side ? Wa1 : Wa0;
  bf16* out = Wn2 + ((size_t)side * 256 + r) * 256;
  for (int k = threadIdx.x; k < 256; k += 256) {
    float v = (r < 200 && k < 200) ? Wa[(size_t)r * K3 + k] : 0.f;
    out[k] = __float2bfloat16(v);
  }
}

// dst[side][rpad][448]: rows < nrows = W_side[r][200:600], rest 0
__global__ __launch_bounds__(256) void k_pack_w400(
    const float* __restrict__ W0, const float* __restrict__ W1,
    bf16* __restrict__ dst, int nrows, int rpad)
{
  int r = blockIdx.x, side = blockIdx.y;
  const float* W = side ? W1 : W0;
  bf16* out = dst + ((size_t)side * rpad + r) * 448;
  for (int k = threadIdx.x; k < 448; k += 256) {
    float v = (r < nrows && k < 400) ? W[(size_t)r * K3 + 200 + k] : 0.f;
    out[k] = __float2bfloat16(v);
  }
}

// GRU weights, wave-access-ordered for perfectly coalesced loads:
// Wpk[side][blk = (wave*14+ks)*3+gate][t=512] where t = l15*32 + quad*8 + e
// value = W[gate*200 + wave*16 + l15][k], k = ks*32 + quad*8 + e (Wc k-layout:
// k<200 -> Wih[.][k]; 224<=k<424 -> Whh[.][k-224]; else 0)
__global__ __launch_bounds__(512) void k_wpk(
    const float* __restrict__ Wih0, const float* __restrict__ Wih1,
    const float* __restrict__ Whh0, const float* __restrict__ Whh1,
    bf16* __restrict__ Wpk)
{
  int blk = blockIdx.x, side = blockIdx.y;
  int wave = blk / 42, rem = blk % 42;
  int ks = rem / 3, gate = rem % 3;
  const float* Wih = side ? Wih1 : Wih0;
  const float* Whh = side ? Whh1 : Whh0;
  int t = threadIdx.x;
  int l15 = t >> 5, quad = (t >> 3) & 3, e = t & 7;
  int rg = wave * 16 + l15;             // row within gate
  int k = ks * 32 + quad * 8 + e;
  float v = 0.f;
  if (rg < 200) {
    int row = gate * 200 + rg;
    if (k < 200) v = Wih[(size_t)row * K3 + k];
    else if (k >= 224 && k < 424) v = Whh[(size_t)row * H_ + (k - 224)];
  }
  Wpk[((size_t)side * 546 + blk) * 512 + t] = __float2bfloat16(v);
}

// A-panels for bias/gibase GEMMs
__global__ __launch_bounds__(256) void k_afeats(
    const float* __restrict__ ent, const float* __restrict__ rel, const int* __restrict__ trip,
    bf16* __restrict__ Ab, bf16* __restrict__ Ag)
{
  int b = blockIdx.x, side = blockIdx.y;
  int ids = trip[b * 3 + (side ? 2 : 0)];
  int rid = trip[b * 3 + 1];
  size_t ro = ((size_t)side * B_ + b) * 448;
  for (int k = threadIdx.x; k < 448; k += 256) {
    float vb = 0.f, vg = 0.f;
    if (k < 200) { float e = ent[(size_t)ids * H_ + k]; vb = e; vg = e; }
    else if (k < 400) {
      vb = ent[(size_t)rid * H_ + (k - 200)];
      vg = rel[(size_t)rid * H_ + (k - 200)];
    }
    Ab[ro + k] = __float2bfloat16(vb);
    Ag[ro + k] = __float2bfloat16(vg);
  }
}

// bf16 copy of ent
__global__ __launch_bounds__(256) void k_entb(
    const float* __restrict__ ent, bf16* __restrict__ entb)
{
  int i0 = (blockIdx.x * 256 + threadIdx.x) * 4;
  #pragma unroll
  for (int u = 0; u < 4; u++) {
    int i = i0 + u;
    if (i < E_ * H_) entb[i] = __float2bfloat16(ent[i]);
  }
}

// ---------------------------------------------------------------- generic MFMA GEMM (tile 128x64, BK=64)
template<bool OUTBF, bool AF32>
__global__ __launch_bounds__(256) void k_gg(
    const void* __restrict__ Aptr, const bf16* __restrict__ Bptr,
    const float* __restrict__ bias0, const float* __restrict__ bias1,
    void* __restrict__ Cptr,
    int M, int Nout, int KP, int Acols,
    long Astride, long Bstride, long Cstride, int Nstride)
{
  int side = blockIdx.z;
  int m0 = blockIdx.x * 128, n0 = blockIdx.y * 64;

  __shared__ bf16 As[128][72];
  __shared__ bf16 Bs[64][72];

  int tid = threadIdx.x;
  int wave = tid >> 6, lane = tid & 63;
  int quad = lane >> 4, l15 = lane & 15;

  f32x4 acc[8];
  #pragma unroll
  for (int mt = 0; mt < 8; mt++) acc[mt] = (f32x4){0,0,0,0};

  int arow = tid >> 1, ac0 = (tid & 1) * 32;
  int gr = m0 + arow; if (gr > M - 1) gr = M - 1;
  int brow = tid >> 2, bc0 = (tid & 3) * 16;

  for (int k0 = 0; k0 < KP; k0 += 64) {
    if (AF32) {
      const float* src = (const float*)Aptr + (size_t)gr * Acols;
      #pragma unroll
      for (int u = 0; u < 8; u++) {
        int kk = k0 + ac0 + u * 4;
        float4 v;
        if (kk + 4 <= Acols) v = *(const float4*)&src[kk];
        else {
          v.x = (kk + 0 < Acols) ? src[kk + 0] : 0.f;
          v.y = (kk + 1 < Acols) ? src[kk + 1] : 0.f;
          v.z = (kk + 2 < Acols) ? src[kk + 2] : 0.f;
          v.w = (kk + 3 < Acols) ? src[kk + 3] : 0.f;
        }
        As[arow][ac0 + u * 4 + 0] = __float2bfloat16(v.x);
        As[arow][ac0 + u * 4 + 1] = __float2bfloat16(v.y);
        As[arow][ac0 + u * 4 + 2] = __float2bfloat16(v.z);
        As[arow][ac0 + u * 4 + 3] = __float2bfloat16(v.w);
      }
    } else {
      const bf16* src = (const bf16*)Aptr + (size_t)side * Astride + (size_t)gr * KP + k0 + ac0;
      #pragma unroll
      for (int u = 0; u < 4; u++)
        *(short8*)&As[arow][ac0 + u * 8] = *(const short8*)&src[u * 8];
    }
    {
      const bf16* src = Bptr + (size_t)side * Bstride + (size_t)(n0 + brow) * KP + k0 + bc0;
      *(short8*)&Bs[brow][bc0]     = *(const short8*)&src[0];
      *(short8*)&Bs[brow][bc0 + 8] = *(const short8*)&src[8];
    }
    __syncthreads();
    #pragma unroll
    for (int ks = 0; ks < 2; ks++) {
      int kk = ks * 32 + quad * 8;
      short8 bfr = *(const short8*)&Bs[wave * 16 + l15][kk];
      #pragma unroll
      for (int mt = 0; mt < 8; mt++) {
        short8 afr = *(const short8*)&As[mt * 16 + l15][kk];
        acc[mt] = __builtin_amdgcn_mfma_f32_16x16x32_bf16(afr, bfr, acc[mt], 0, 0, 0);
      }
    }
    __syncthreads();
  }

  int n = n0 + wave * 16 + l15;
  if (n < Nout) {
    float bv = bias0 ? (side ? bias1[n] : bias0[n]) : 0.f;
    #pragma unroll
    for (int mt = 0; mt < 8; mt++) {
      #pragma unroll
      for (int r = 0; r < 4; r++) {
        int m = m0 + mt * 16 + quad * 4 + r;
        if (m < M) {
          float val = acc[mt][r] + bv;
          if (OUTBF)
            ((bf16*)Cptr)[(size_t)side * Cstride + (size_t)m * Nstride + n] = __float2bfloat16(val);
          else
            ((float*)Cptr)[(size_t)side * Cstride + (size_t)m * Nstride + n] = val;
        }
      }
    }
  }
}

// ---------------------------------------------------------------- attention -> step[side][b][t][h] (bf16, masked)
// ep2s[side][e][g], entb bf16
__global__ __launch_bounds__(256) void k_attn(
    const bf16* __restrict__ entb,
    const int* __restrict__ neigh0, const int* __restrict__ neigh1,
    const int* __restrict__ nlen0, const int* __restrict__ nlen1,
    const int* __restrict__ hlen0, const int* __restrict__ hlen1,
    const float* __restrict__ v0, const float* __restrict__ v1,
    const bf16* __restrict__ ep2s, const float* __restrict__ biasb,
    bf16* __restrict__ stepb)
{
  int side = blockIdx.y;
  int bt = blockIdx.x;
  int b = bt / T_, t = bt % T_;
  const int* hlenA = side ? hlen1 : hlen0;
  int hl = hlenA[b];
  if (t >= hl) {
    int h = threadIdx.x;
    if (h < H_) stepb[(((size_t)side * B_ + b) * T_ + t) * H_ + h] = __float2bfloat16(0.f);
    return;
  }
  const int* neigh = side ? neigh1 : neigh0;
  const int* nlenA = side ? nlen1 : nlen0;
  const float* v = side ? v1 : v0;
  const bf16* epo = ep2s + (size_t)side * E_ * H_;
  const float* brow = biasb + ((size_t)side * B_ + b) * H_;

  __shared__ float bsh[H_], vsh[H_], lg[64], wsh[64];
  __shared__ int nb[N_];
  int tid = threadIdx.x;
  if (tid < H_) { bsh[tid] = brow[tid]; vsh[tid] = v[tid]; }
  if (tid < N_) nb[tid] = neigh[((size_t)b * T_ + t) * N_ + tid];
  int nl = nlenA[b * T_ + t];
  __syncthreads();

  int wave = tid >> 6, lane = tid & 63;
  for (int n = wave; n < nl; n += 4) {
    float acc = 0.f;
    const bf16* er = epo + (size_t)nb[n] * H_;
    for (int g = lane; g < H_; g += 64) acc += tanhf(b2f(er[g]) + bsh[g]) * vsh[g];
    for (int off = 32; off > 0; off >>= 1) acc += __shfl_down(acc, off);
    if (lane == 0) lg[n] = acc;
  }
  __syncthreads();
  if (tid < 64) {
    float x = (tid < nl) ? lg[tid] : -1e30f;
    float m = x;
    for (int off = 32; off > 0; off >>= 1) m = fmaxf(m, __shfl_down(m, off));
    m = __shfl(m, 0);
    float e = (tid < nl) ? expf(x - m) : 0.f;
    float s = e;
    for (int off = 32; off > 0; off >>= 1) s += __shfl_down(s, off);
    s = __shfl(s, 0);
    if (tid < N_) wsh[tid] = e / s;
  }
  __syncthreads();
  int h = tid;
  if (h < H_) {
    float st = 0.f;
    for (int n = 0; n < nl; n++) st += wsh[n] * b2f(entb[(size_t)nb[n] * H_ + h]);
    stepb[(((size_t)side * B_ + b) * T_ + t) * H_ + h] = __float2bfloat16(st);
  }
}

// ---------------------------------------------------------------- MFMA GRU v4 — coalesced Wpk weight loads
__global__ __launch_bounds__(832) void k_gru4(
    const bf16* __restrict__ stepb, const bf16* __restrict__ gibase,
    const bf16* __restrict__ Wpk,
    const float* __restrict__ bhh0, const float* __restrict__ bhh1,
    const int* __restrict__ len0, const int* __restrict__ len1,
    float* __restrict__ hfin)
{
  int side = blockIdx.y;
  int b0 = blockIdx.x * 16;
  const bf16* stp = stepb + (size_t)side * B_ * T_ * H_;
  const bf16* gib = gibase + ((size_t)side * B_ + b0) * K3;
  const float* bhh = side ? bhh1 : bhh0;
  const int* len = side ? len1 : len0;

  __shared__ bf16 Ax[16][456];

  int tid = threadIdx.x;
  int wave = tid >> 6, lane = tid & 63;
  int quad = lane >> 4, l15 = lane & 15;

  for (int i = tid; i < 16 * 456 / 8; i += 832) ((short8*)&Ax[0][0])[i] = (short8)0;
  __syncthreads();
  for (int i = tid; i < 16 * 25; i += 832) {
    int row = i / 25, seg = i % 25;
    *(short8*)&Ax[row][seg * 8] =
        *(const short8*)&stp[(((size_t)(b0 + row)) * T_ + 0) * H_ + seg * 8];
  }

  int j = wave * 16 + l15;
  bool jok = (j < H_);
  float bhr = 0.f, bhz = 0.f, bhn = 0.f;
  float gr[4] = {}, gz[4] = {}, gn[4] = {};
  int lens4[4];
  #pragma unroll
  for (int r = 0; r < 4; r++) lens4[r] = len[b0 + quad * 4 + r];
  if (jok) {
    bhr = bhh[j]; bhz = bhh[H_ + j]; bhn = bhh[2 * H_ + j];
    #pragma unroll
    for (int r = 0; r < 4; r++) {
      const bf16* g = gib + (size_t)(quad * 4 + r) * K3;
      gr[r] = b2f(g[j]); gz[r] = b2f(g[H_ + j]); gn[r] = b2f(g[2 * H_ + j]);
    }
  }
  // coalesced weight chunks: base for this wave; per (ks,gate) one contiguous 1 KB block
  const short8* Wv = (const short8*)(Wpk + ((size_t)side * 546 + (size_t)wave * 42) * 512);
  int lidx = l15 * 4 + quad;   // 16-B chunk index within the 1 KB block
  __syncthreads();

  for (int t = 0; t < T_; t++) {
    f32x4 ar = {0,0,0,0}, az = {0,0,0,0}, ani = {0,0,0,0}, anh = {0,0,0,0};
    #pragma unroll
    for (int ks = 0; ks < 14; ks++) {
      int kk = ks * 32 + quad * 8;
      short8 a0 = *(const short8*)&Ax[l15][kk];
      short8 br = Wv[(ks * 3 + 0) * 64 + lidx];
      short8 bz = Wv[(ks * 3 + 1) * 64 + lidx];
      short8 bn = Wv[(ks * 3 + 2) * 64 + lidx];
      ar = __builtin_amdgcn_mfma_f32_16x16x32_bf16(a0, br, ar, 0, 0, 0);
      az = __builtin_amdgcn_mfma_f32_16x16x32_bf16(a0, bz, az, 0, 0, 0);
      if (ks < 7) ani = __builtin_amdgcn_mfma_f32_16x16x32_bf16(a0, bn, ani, 0, 0, 0);
      else        anh = __builtin_amdgcn_mfma_f32_16x16x32_bf16(a0, bn, anh, 0, 0, 0);
    }
    bf16 hnew_b[4];
    if (jok) {
      #pragma unroll
      for (int r = 0; r < 4; r++) {
        int row = quad * 4 + r;
        float rz = ar[r] + gr[r] + bhr;
        float zz = az[r] + gz[r] + bhz;
        float inn = ani[r] + gn[r];
        float hn  = anh[r] + bhn;
        float rg = sigm(rz);
        float zg = sigm(zz);
        float ng = tanhf(inn + rg * hn);
        float hold = b2f(Ax[row][224 + j]);
        float hnew = (1.f - zg) * ng + zg * hold;
        hnew_b[r] = __float2bfloat16((t < lens4[r]) ? hnew : hold);
      }
    }
    __syncthreads();
    if (jok) {
      #pragma unroll
      for (int r = 0; r < 4; r++) Ax[quad * 4 + r][224 + j] = hnew_b[r];
    }
    if (t < T_ - 1) {
      for (int i = tid; i < 16 * 25; i += 832) {
        int row = i / 25, seg = i % 25;
        *(short8*)&Ax[row][seg * 8] =
            *(const short8*)&stp[(((size_t)(b0 + row)) * T_ + (t + 1)) * H_ + seg * 8];
      }
    }
    __syncthreads();
  }
  for (int i = tid; i < 16 * H_; i += 832) {
    int row = i / H_, jj = i % H_;
    hfin[((size_t)side * B_ + b0 + row) * H_ + jj] = b2f(Ax[row][224 + jj]);
  }
}

// ---------------------------------------------------------------- stable descending argsort of hist_len
__global__ __launch_bounds__(512) void k_argsort(
    const int* __restrict__ hlen0, const int* __restrict__ hlen1,
    int* __restrict__ idxbuf, float* __restrict__ dout)
{
  int side = blockIdx.x;
  const int* len = side ? hlen1 : hlen0;
  __shared__ int lens[B_];
  __shared__ int perm[B_];
  int tid = threadIdx.x;
  lens[tid] = len[tid];
  __syncthreads();
  int L = lens[tid];
  int rank = 0;
  for (int j = 0; j < B_; j++) {
    int Lj = lens[j];
    rank += (Lj > L) || (Lj == L && j < tid);
  }
  perm[rank] = tid;
  __syncthreads();
  idxbuf[side * B_ + tid] = perm[tid];
  size_t base = 1 + (size_t)2 * B_ * E_ + (side ? 0 : B_);
  dout[base + tid] = (float)perm[tid];
}

// ---------------------------------------------------------------- assemble pred-GEMM input rows (bf16, K padded to 640)
__global__ __launch_bounds__(256) void k_feat(
    const float* __restrict__ ent, const float* __restrict__ rel, const int* __restrict__ trip,
    const int* __restrict__ idxbuf, const float* __restrict__ hfin,
    bf16* __restrict__ xfeat)
{
  int i = blockIdx.x, p = blockIdx.y;
  int bi = idxbuf[(p == 0 ? 1 : 0) * B_ + i];
  int ent_id = (p == 0) ? trip[bi * 3 + 2] : trip[bi * 3 + 0];
  int rid = trip[bi * 3 + 1];
  const float* hsrc = hfin + (size_t)(p == 0 ? 1 : 0) * B_ * H_;
  bf16* x = xfeat + ((size_t)p * B_ + i) * 640;
  int h = threadIdx.x;
  if (h < H_) {
    x[h]          = __float2bfloat16(ent[(size_t)ent_id * H_ + h]);
    x[H_ + h]     = __float2bfloat16(hsrc[(size_t)bi * H_ + h]);
    x[2 * H_ + h] = __float2bfloat16(rel[(size_t)rid * H_ + h]);
  }
  if (h < 40) x[600 + h] = __float2bfloat16(0.f);
}

// ---------------------------------------------------------------- MFMA pred GEMM, M-tile 256 (halves B passes)
__global__ __launch_bounds__(256) void k_gemm3(
    const bf16* __restrict__ Abf,
    const float* __restrict__ B0, const float* __restrict__ B1,
    const float* __restrict__ bias0, const float* __restrict__ bias1,
    float* __restrict__ dout)
{
  int side = blockIdx.z;
  const float* Bm = side ? B1 : B0;
  const float* bias = side ? bias1 : bias0;
  float* C = dout + 1 + (size_t)side * B_ * E_;
  int mBase = blockIdx.x * 256;             // 0 or 256 within side
  int m0 = side * B_ + mBase;
  int n0 = blockIdx.y * 64;

  __shared__ bf16 As[256][72];
  __shared__ bf16 Bs[64][72];

  int tid = threadIdx.x;
  int wave = tid >> 6, lane = tid & 63;
  int quad = lane >> 4, l15 = lane & 15;

  f32x4 acc[16];
  #pragma unroll
  for (int mt = 0; mt < 16; mt++) acc[mt] = (f32x4){0,0,0,0};

  int brow = tid >> 2, bc0 = (tid & 3) * 16;

  for (int k0 = 0; k0 < 640; k0 += 64) {
    // stage A: 256 rows x 64 cols bf16, one row per thread
    {
      const bf16* src = Abf + (size_t)(m0 + tid) * 640 + k0;
      #pragma unroll
      for (int u = 0; u < 8; u++)
        *(short8*)&As[tid][u * 8] = *(const short8*)&src[u * 8];
    }
    // stage B: 64 x 64 fp32 -> bf16
    {
      int n = n0 + brow;
      if (n < E_ && k0 + bc0 + 16 <= K3) {
        const float* src = Bm + (size_t)n * K3 + k0 + bc0;
        #pragma unroll
        for (int u = 0; u < 16; u += 4) {
          float4 v = *(const float4*)&src[u];
          Bs[brow][bc0 + u + 0] = __float2bfloat16(v.x);
          Bs[brow][bc0 + u + 1] = __float2bfloat16(v.y);
          Bs[brow][bc0 + u + 2] = __float2bfloat16(v.z);
          Bs[brow][bc0 + u + 3] = __float2bfloat16(v.w);
        }
      } else {
        #pragma unroll
        for (int u = 0; u < 16; u++) {
          int k = k0 + bc0 + u;
          float v = (n < E_ && k < K3) ? Bm[(size_t)n * K3 + k] : 0.f;
          Bs[brow][bc0 + u] = __float2bfloat16(v);
        }
      }
    }
    __syncthreads();
    #pragma unroll
    for (int ks = 0; ks < 2; ks++) {
      int kk = ks * 32 + quad * 8;
      short8 bfr = *(const short8*)&Bs[wave * 16 + l15][kk];
      #pragma unroll
      for (int mt = 0; mt < 16; mt++) {
        short8 afr = *(const short8*)&As[mt * 16 + l15][kk];
        acc[mt] = __builtin_amdgcn_mfma_f32_16x16x32_bf16(afr, bfr, acc[mt], 0, 0, 0);
      }
    }
    __syncthreads();
  }

  int n = n0 + wave * 16 + l15;
  if (n < E_) {
    float bv = bias[n];
    #pragma unroll
    for (int mt = 0; mt < 16; mt++) {
      #pragma unroll
      for (int r = 0; r < 4; r++) {
        int mrow = mBase + mt * 16 + quad * 4 + r;
        C[(size_t)mrow * E_ + n] = acc[mt][r] + bv;
      }
    }
  }
}

// ---------------------------------------------------------------- CE loss, online softmax
__global__ __launch_bounds__(256) void k_loss(
    const float* __restrict__ dout, const int* __restrict__ trip,
    const int* __restrict__ idxbuf, float* __restrict__ lossacc)
{
  int i = blockIdx.x, p = blockIdx.y;
  const float* row = dout + 1 + (size_t)p * B_ * E_ + (size_t)i * E_;
  int tid = threadIdx.x;
  float m = -1e30f, s = 0.f;
  for (int e = tid; e < E_; e += 256) {
    float x = row[e];
    if (x > m) { s = s * expf(m - x) + 1.f; m = x; }
    else s += expf(x - m);
  }
  __shared__ float ms[256], ss[256];
  ms[tid] = m; ss[tid] = s; __syncthreads();
  for (int st = 128; st > 0; st >>= 1) {
    if (tid < st) {
      float m2 = ms[tid + st], s2 = ss[tid + st];
      float m1 = ms[tid], s1 = ss[tid];
      float mm = fmaxf(m1, m2);
      ss[tid] = s1 * expf(m1 - mm) + s2 * expf(m2 - mm);
      ms[tid] = mm;
    }
    __syncthreads();
  }
  if (tid == 0) {
    int bi = idxbuf[(p == 0 ? 1 : 0) * B_ + i];
    int label = (p == 0) ? trip[bi * 3 + 0] : trip[bi * 3 + 2];
    float lp = row[label] - ms[0] - logf(ss[0]);
    atomicAdd(lossacc, -lp / (float)B_);
  }
}

__global__ void k_loss_write(const float* __restrict__ lossacc, float* __restrict__ dout){
  if (threadIdx.x == 0) dout[0] = lossacc[0];
}

// ----------------------------------------------------------------
extern "C" void kernel_launch(void* const* d_in, const int* in_sizes, int n_in,
                              void* d_out, int out_size, void* d_ws, size_t ws_size,
                              hipStream_t stream)
{
  const int* trip = (const int*)d_in[0];
  const int* s_ne = (const int*)d_in[1];
  const int* s_nl = (const int*)d_in[2];
  const int* s_hl = (const int*)d_in[3];
  const int* o_ne = (const int*)d_in[4];
  const int* o_nl = (const int*)d_in[5];
  const int* o_hl = (const int*)d_in[6];
  const float* ent = (const float*)d_in[7];
  const float* rel = (const float*)d_in[8];
  const float* aw_s = (const float*)d_in[9];
  const float* ab_s = (const float*)d_in[10];
  const float* v_s  = (const float*)d_in[11];
  const float* aw_o = (const float*)d_in[12];
  const float* ab_o = (const float*)d_in[13];
  const float* v_o  = (const float*)d_in[14];
  const float* sub_wih = (const float*)d_in[15];
  const float* sub_whh = (const float*)d_in[16];
  const float* sub_bih = (const float*)d_in[17];
  const float* sub_bhh = (const float*)d_in[18];
  const float* ob_wih  = (const float*)d_in[19];
  const float* ob_whh  = (const float*)d_in[20];
  const float* ob_bih  = (const float*)d_in[21];
  const float* ob_bhh  = (const float*)d_in[22];
  const float* lin_sub_w = (const float*)d_in[23];
  const float* lin_sub_b = (const float*)d_in[24];
  const float* lin_ob_w  = (const float*)d_in[25];
  const float* lin_ob_b  = (const float*)d_in[26];
  float* dout = (float*)d_out;

  // workspace carve — total ~25.1 MB
  char* w = (char*)d_ws;
  bf16* ep2s    = (bf16*)w;  w += (size_t)2 * E_ * H_ * 2;        // 8,000,000 B
  bf16* stepb   = (bf16*)w;  w += (size_t)2 * B_ * T_ * H_ * 2;   // 4,096,000 B
  float* biasb  = (float*)w; w += (size_t)2 * B_ * H_ * 4;        //   819,200 B
  bf16* gibase  = (bf16*)w;  w += (size_t)2 * B_ * K3 * 2;        // 1,228,800 B
  float* hfin   = (float*)w; w += (size_t)2 * B_ * H_ * 4;        //   819,200 B
  bf16* xfeat   = (bf16*)w;  w += (size_t)1024 * 640 * 2;         // 1,310,720 B
  bf16* Wpk     = (bf16*)w;  w += (size_t)2 * 546 * 512 * 2;      // 1,118,208 B
  bf16* Wn2     = (bf16*)w;  w += (size_t)2 * 256 * 256 * 2;      //   262,144 B
  bf16* Wb2     = (bf16*)w;  w += (size_t)2 * 256 * 448 * 2;      //   458,752 B
  bf16* Wg2     = (bf16*)w;  w += (size_t)2 * 640 * 448 * 2;      // 1,146,880 B
  bf16* Abias   = (bf16*)w;  w += (size_t)2 * B_ * 448 * 2;       //   917,504 B
  bf16* Agi     = (bf16*)w;  w += (size_t)2 * B_ * 448 * 2;       //   917,504 B
  bf16* entb    = (bf16*)w;  w += (size_t)E_ * H_ * 2;            // 4,000,000 B
  float* lossacc= (float*)w; w += 256;
  int* idxbuf   = (int*)w;   w += 4096;

  k_init<<<1, 64, 0, stream>>>(lossacc);
  // packs
  k_pack_wn2<<<dim3(256, 2), 256, 0, stream>>>(aw_s, aw_o, Wn2);
  k_pack_w400<<<dim3(256, 2), 256, 0, stream>>>(aw_s, aw_o, Wb2, 200, 256);
  k_pack_w400<<<dim3(640, 2), 256, 0, stream>>>(sub_wih, ob_wih, Wg2, 600, 640);
  k_wpk<<<dim3(546, 2), 512, 0, stream>>>(sub_wih, ob_wih, sub_whh, ob_whh, Wpk);
  k_afeats<<<dim3(B_, 2), 256, 0, stream>>>(ent, rel, trip, Abias, Agi);
  k_entb<<<(E_ * H_ + 1023) / 1024, 256, 0, stream>>>(ent, entb);
  // ep2s[side][e][g] = ent @ Wn_side.T   (M=10000, N=200, K=256pad, A shared fp32)
  k_gg<true, true><<<dim3(79, 4, 2), 256, 0, stream>>>(
      (const void*)ent, Wn2, nullptr, nullptr, (void*)ep2s,
      E_, 200, 256, 200, 0L, 256L * 256, (long)E_ * 200, 200);
  // biasb = [se;re] @ Wa[:,200:600].T + ba
  k_gg<false, false><<<dim3(4, 4, 2), 256, 0, stream>>>(
      (const void*)Abias, Wb2, ab_s, ab_o, (void*)biasb,
      B_, 200, 448, 448, (long)B_ * 448, 256L * 448, (long)B_ * 200, 200);
  // gibase = [se;rr] @ Wih[:,200:600].T + bih
  k_gg<true, false><<<dim3(4, 10, 2), 256, 0, stream>>>(
      (const void*)Agi, Wg2, sub_bih, ob_bih, (void*)gibase,
      B_, 600, 448, 448, (long)B_ * 448, 640L * 448, (long)B_ * 600, 600);
  // attention
  k_attn<<<dim3(B_ * T_, 2), 256, 0, stream>>>(entb, s_ne, o_ne, s_nl, o_nl,
                                               s_hl, o_hl, v_s, v_o, ep2s, biasb, stepb);
  // GRU
  k_gru4<<<dim3(B_ / 16, 2), 832, 0, stream>>>(stepb, gibase, Wpk, sub_bhh, ob_bhh,
                                               s_hl, o_hl, hfin);
  k_argsort<<<2, 512, 0, stream>>>(s_hl, o_hl, idxbuf, dout);
  k_feat<<<dim3(B_, 2), 256, 0, stream>>>(ent, rel, trip, idxbuf, hfin, xfeat);
  k_gemm3<<<dim3(2, (E_ + 63) / 64, 2), 256, 0, stream>>>(
      xfeat, lin_ob_w, lin_sub_w, lin_ob_b, lin_sub_b, dout);
  k_loss<<<dim3(B_, 2), 256, 0, stream>>>(dout, trip, idxbuf, lossacc);
  k_loss_write<<<1, 64, 0, stream>>>(lossacc, dout);
}